// Round 8
// baseline (2796.133 us; speedup 1.0000x reference)
//
#include <hip/hip_runtime.h>
#include <hip/hip_bf16.h>

// ---- problem constants ----
#define D_MODELc 1024
#define D_INNERc 2048
#define NHEADSc  32
#define LSEQc    2048
#define BSZc     2
#define NPROJc   4256   // 2*D_INNER + 2*64 + 32
#define PAIRSc   16
#define ROWSc    (BSZc*LSEQc)   // 4096
#define BCDTc    160            // B(64) + C(64) + dt(32) columns

typedef __attribute__((ext_vector_type(4))) float f4;
typedef __attribute__((ext_vector_type(2))) float f2;
typedef __attribute__((ext_vector_type(8))) short s16x8;
typedef __attribute__((ext_vector_type(4))) float f32x4;
typedef __attribute__((ext_vector_type(4))) unsigned int u32x4;
typedef __attribute__((ext_vector_type(4))) unsigned short u16x4;

static __device__ __forceinline__ unsigned short f2bf(float f) {
  unsigned u = __float_as_uint(f);
  unsigned r = (u + 0x7fffu + ((u >> 16) & 1u)) >> 16;
  return (unsigned short)r;
}

// ---------------- convert f32 -> bf16 (vectorized) ----------------
__global__ void cvt_bf16_kernel(const float* __restrict__ in, unsigned short* __restrict__ out, int n4) {
  int i = blockIdx.x * blockDim.x + threadIdx.x;
  if (i < n4) {
    f4 v = *(const f4*)(in + (size_t)i * 4);
    u16x4 o = { f2bf(v[0]), f2bf(v[1]), f2bf(v[2]), f2bf(v[3]) };
    *(u16x4*)(out + (size_t)i * 4) = o;
  }
}

// ---------------- transpose f32 [R][C] -> bf16 [C][R] ----------------
__global__ void transpose_to_bf16(const float* __restrict__ in, unsigned short* __restrict__ out,
                                  int R, int C) {
  __shared__ float t[32][33];
  int c0 = blockIdx.x * 32, r0 = blockIdx.y * 32;
  int tx = threadIdx.x, ty = threadIdx.y; // block (32,8)
  #pragma unroll
  for (int i = 0; i < 32; i += 8)
    t[ty + i][tx] = in[(size_t)(r0 + ty + i) * C + c0 + tx];
  __syncthreads();
  #pragma unroll
  for (int i = 0; i < 32; i += 8)
    out[(size_t)(c0 + ty + i) * R + r0 + tx] = f2bf(t[tx][ty + i]);
}

// ---------------- transpose BCdt weight block to f32 [160][1024] ----------------
__global__ void transpose_bcdt_f32(const float* __restrict__ W, float* __restrict__ wt) {
  int idx = blockIdx.x * 256 + threadIdx.x;    // 160*1024 = 163840
  int j = idx >> 10, k = idx & 1023;           // wt[j][k] = W[k][4096+j]
  wt[idx] = W[(size_t)k * NPROJc + 2 * D_INNERc + j];
}

// ---------------- exact fp32 GEMM for B/C/dt columns ----------------
// zx[r][4096+j] = sum_k x[r][k] * wt[j][k]   (r<4096, j<160)
__global__ __launch_bounds__(256) void gemm_f32_bcdt(
    const float* __restrict__ x, const float* __restrict__ wt,
    float* __restrict__ zx) {
  int tid = threadIdx.x;
  int r = blockIdx.x * 8 + (tid >> 5);
  int j = blockIdx.y * 32 + (tid & 31);
  const f4* xr = (const f4*)(x + (size_t)r * D_MODELc);
  const f4* wr = (const f4*)(wt + (size_t)j * D_MODELc);
  float acc = 0.f;
  #pragma unroll 8
  for (int k = 0; k < D_MODELc / 4; ++k) {
    f4 a = xr[k], b = wr[k];
    acc = fmaf(a[0], b[0], acc);
    acc = fmaf(a[1], b[1], acc);
    acc = fmaf(a[2], b[2], acc);
    acc = fmaf(a[3], b[3], acc);
  }
  zx[(size_t)r * NPROJc + 2 * D_INNERc + j] = acc;
}

// ---------------- bf16 MFMA GEMM:  C[M][N] = A[M][K] * Bt[N][K]^T ----------------
#define BMt 128
#define BNt 128
#define BKt 64
__global__ __launch_bounds__(256) void gemm_bf16_bt(
    const unsigned short* __restrict__ A,   // [M][K] bf16 bits
    const unsigned short* __restrict__ Bt,  // [N][K] bf16 bits
    float* __restrict__ C,                  // [M][N] f32 (row stride = N)
    int M, int N, int K) {
  __shared__ unsigned short sA[BMt * BKt];
  __shared__ unsigned short sB[BNt * BKt];
  int tid = threadIdx.x;
  int lane = tid & 63;
  int wave = tid >> 6;
  int bm = blockIdx.x * BMt;
  int bn = blockIdx.y * BNt;
  int wr = (wave >> 1) * 64;
  int wc = (wave & 1) * 64;
  f32x4 acc[4][4];
  #pragma unroll
  for (int i = 0; i < 4; ++i)
    #pragma unroll
    for (int j = 0; j < 4; ++j) acc[i][j] = (f32x4){0.f, 0.f, 0.f, 0.f};
  int lr = lane & 15, lg = lane >> 4;
  for (int k0 = 0; k0 < K; k0 += BKt) {
    __syncthreads();
    #pragma unroll
    for (int q = 0; q < 4; ++q) {
      int c = tid + 256 * q;           // 0..1023: 128 rows x 8 chunks of 8 bf16
      int r = c >> 3, ch = c & 7;
      int sw = ch ^ (r & 7);           // XOR swizzle kills stride-128B bank conflict
      u32x4 va = *(const u32x4*)(A + (size_t)(bm + r) * K + k0 + ch * 8);
      *(u32x4*)(sA + r * BKt + sw * 8) = va;
      u32x4 vb = (u32x4){0u, 0u, 0u, 0u};
      if (bn + r < N) vb = *(const u32x4*)(Bt + (size_t)(bn + r) * K + k0 + ch * 8);
      *(u32x4*)(sB + r * BKt + sw * 8) = vb;
    }
    __syncthreads();
    #pragma unroll
    for (int kk = 0; kk < BKt; kk += 32) {
      s16x8 af[4], bfr[4];
      int ch = (kk >> 3) + lg;
      #pragma unroll
      for (int i = 0; i < 4; ++i) {
        int row = wr + i * 16 + lr;
        af[i] = *(const s16x8*)(sA + row * BKt + (ch ^ (row & 7)) * 8);
        int col = wc + i * 16 + lr;
        bfr[i] = *(const s16x8*)(sB + col * BKt + (ch ^ (col & 7)) * 8);
      }
      #pragma unroll
      for (int i = 0; i < 4; ++i)
        #pragma unroll
        for (int j = 0; j < 4; ++j)
          acc[i][j] = __builtin_amdgcn_mfma_f32_16x16x32_bf16(af[i], bfr[j], acc[i][j], 0, 0, 0);
    }
  }
  // C/D layout (HW-verified): col = lane&15, row = (lane>>4)*4 + reg
  #pragma unroll
  for (int i = 0; i < 4; ++i) {
    #pragma unroll
    for (int j = 0; j < 4; ++j) {
      int col = bn + wc + j * 16 + lr;
      if (col < N) {
        #pragma unroll
        for (int r = 0; r < 4; ++r) {
          int row = bm + wr + i * 16 + lg * 4 + r;
          C[(size_t)row * N + col] = acc[i][j][r];
        }
      }
    }
  }
}

// ---------------- prep: softplus/decay + rope cos/sin tables ----------------
__global__ void prep_kernel(const float* __restrict__ zx, const float* __restrict__ dt_bias,
                            const float* __restrict__ A_log, float* __restrict__ dtdec,
                            float* __restrict__ cstab) {
  int idx = blockIdx.x * 256 + threadIdx.x;   // (b*L + l)*32 + h, 131072 total
  int h = idx & 31;
  int bl = idx >> 5;
  float raw = zx[(size_t)bl * NPROJc + (2 * D_INNERc + 128) + h] + dt_bias[h];
  // numerically stable softplus
  float dt = fmaxf(raw, 0.f) + log1pf(expf(-fabsf(raw)));
  float dec = expf(-expf(A_log[h]) * dt);
  dtdec[(size_t)idx * 2] = dt;
  dtdec[(size_t)idx * 2 + 1] = dec;
  #pragma unroll
  for (int k = 0; k < PAIRSc; ++k) {
    float invf = expf(-(float)k * 0.575646273248511f); // ln(10000)/16
    float ang = dt * invf;
    float sv, cv;
    sincosf(ang, &sv, &cv);
    cstab[((size_t)idx * PAIRSc + k) * 2] = cv;
    cstab[((size_t)idx * PAIRSc + k) * 2 + 1] = sv;
  }
}

// ---------------- sequential scan ----------------
// grid = B*H = 64 blocks, 256 threads (4 waves). lane = p. wave w owns
// rope n in [8w, 8w+8) (pairs 4w..4w+4) and plain n in [32+8w, 32+8w+8).
// Partial y combined via global atomicAdd (no per-step barrier -> prefetch survives).
__global__ __launch_bounds__(256, 1) void scan_kernel(
    const float* __restrict__ zx, const float* __restrict__ dtdec,
    const float* __restrict__ cstab, const float* __restrict__ Dskip,
    float* __restrict__ yout) {
  int bh = blockIdx.x;
  int b = bh >> 5, h = bh & 31;
  int tid = threadIdx.x;
  int w = __builtin_amdgcn_readfirstlane(tid >> 6);
  int p = tid & 63;
  float hr[16];
  #pragma unroll
  for (int i = 0; i < 16; ++i) hr[i] = 0.f;
  float dsk = Dskip[h];
  const float* zrow = zx + (size_t)b * LSEQc * NPROJc;
  const float* ddp = dtdec + ((size_t)b * LSEQc * NHEADSc + h) * 2;
  const float* csp = cstab + (((size_t)b * LSEQc * NHEADSc + h) * PAIRSc + 4 * w) * 2;
  int xoff   = D_INNERc + h * 64 + p;
  int brope  = 2 * D_INNERc + 8 * w;
  int bplain = 2 * D_INNERc + 32 + 8 * w;
  int crope  = 2 * D_INNERc + 64 + 8 * w;
  int cplain = 2 * D_INNERc + 64 + 32 + 8 * w;
  float* yrow = yout + (size_t)b * LSEQc * D_INNERc + h * 64 + p;

  f4 br0a, br0b, bp0a, bp0b, cr0a, cr0b, cq0a, cq0b, cv0a, cv0b; float dt0, dec0, xv0;
  f4 br1a, br1b, bp1a, bp1b, cr1a, cr1b, cq1a, cq1b, cv1a, cv1b; float dt1, dec1, xv1;

#define LOADS(SFX, T) do { \
    const float* zr_ = zrow + (size_t)(T) * NPROJc; \
    br##SFX##a = *(const f4*)(zr_ + brope);      br##SFX##b = *(const f4*)(zr_ + brope + 4); \
    bp##SFX##a = *(const f4*)(zr_ + bplain);     bp##SFX##b = *(const f4*)(zr_ + bplain + 4); \
    cr##SFX##a = *(const f4*)(zr_ + crope);      cr##SFX##b = *(const f4*)(zr_ + crope + 4); \
    cq##SFX##a = *(const f4*)(zr_ + cplain);     cq##SFX##b = *(const f4*)(zr_ + cplain + 4); \
    cv##SFX##a = *(const f4*)(csp + (size_t)(T) * (NHEADSc * PAIRSc * 2)); \
    cv##SFX##b = *(const f4*)(csp + (size_t)(T) * (NHEADSc * PAIRSc * 2) + 4); \
    f2 dd_ = *(const f2*)(ddp + (size_t)(T) * (NHEADSc * 2)); \
    dt##SFX = dd_.x; dec##SFX = dd_.y; \
    xv##SFX = zr_[xoff]; \
  } while (0)

#define STEP(SFX, T, TN) do { \
    float dec_ = dec##SFX; \
    float xv_ = xv##SFX; \
    float dxp_ = dt##SFX * xv_; \
    float yp_ = 0.f; \
    _Pragma("unroll") \
    for (int k = 0; k < 4; ++k) { \
      f4 cvv = (k < 2) ? cv##SFX##a : cv##SFX##b; \
      float c_ = cvv[(k & 1) * 2], s_ = cvv[(k & 1) * 2 + 1]; \
      float cd_ = dec_ * c_, sd_ = dec_ * s_; \
      f4 bv = (k < 2) ? br##SFX##a : br##SFX##b; \
      float b1_ = bv[(2 * k) & 3], b2_ = bv[(2 * k + 1) & 3]; \
      f4 cvC = (k < 2) ? cr##SFX##a : cr##SFX##b; \
      float c1_ = cvC[(2 * k) & 3], c2_ = cvC[(2 * k + 1) & 3]; \
      float h1_ = hr[2 * k], h2_ = hr[2 * k + 1]; \
      float n1_ = fmaf(cd_, h1_, fmaf(-sd_, h2_, b1_ * dxp_)); \
      float n2_ = fmaf(sd_, h1_, fmaf(cd_, h2_, b2_ * dxp_)); \
      hr[2 * k] = n1_; hr[2 * k + 1] = n2_; \
      yp_ = fmaf(c1_, n1_, yp_); \
      yp_ = fmaf(c2_, n2_, yp_); \
    } \
    _Pragma("unroll") \
    for (int i = 0; i < 8; ++i) { \
      f4 bv = (i < 4) ? bp##SFX##a : bp##SFX##b; \
      f4 cv_ = (i < 4) ? cq##SFX##a : cq##SFX##b; \
      float hn_ = fmaf(dec_, hr[8 + i], bv[i & 3] * dxp_); \
      hr[8 + i] = hn_; \
      yp_ = fmaf(cv_[i & 3], hn_, yp_); \
    } \
    if ((TN) < LSEQc) LOADS(SFX, TN); \
    if (w == 0) yp_ = fmaf(dsk, xv_, yp_); \
    atomicAdd(yrow + (size_t)(T) * D_INNERc, yp_); \
  } while (0)

  LOADS(0, 0);
  LOADS(1, 1);
  for (int t = 0; t < LSEQc; t += 2) {
    STEP(0, t, t + 2);
    STEP(1, t + 1, t + 3);
  }
#undef LOADS
#undef STEP
}

// ---------------- fused silu-gate + RMSNorm -> bf16 ----------------
__global__ __launch_bounds__(256) void epilogue_kernel(
    const float* __restrict__ yout, const float* __restrict__ zx,
    const float* __restrict__ nw, unsigned short* __restrict__ gn) {
  int r = blockIdx.x;
  int tid = threadIdx.x;
  const float* yr = yout + (size_t)r * D_INNERc;
  const float* zr = zx + (size_t)r * NPROJc;   // z = first 2048 cols
  float g[8];
  float ss = 0.f;
  #pragma unroll
  for (int q = 0; q < 2; ++q) {
    int j = tid * 4 + q * 1024;
    f4 y = *(const f4*)(yr + j);
    f4 z = *(const f4*)(zr + j);
    #pragma unroll
    for (int e = 0; e < 4; ++e) {
      float zz = z[e];
      float sig = 1.f / (1.f + expf(-zz));
      float gg = y[e] * zz * sig;
      g[q * 4 + e] = gg;
      ss = fmaf(gg, gg, ss);
    }
  }
  #pragma unroll
  for (int o = 1; o < 64; o <<= 1) ss += __shfl_xor(ss, o);
  __shared__ float red[4];
  int wv = tid >> 6, lane = tid & 63;
  if (lane == 0) red[wv] = ss;
  __syncthreads();
  float tot = red[0] + red[1] + red[2] + red[3];
  float scale = rsqrtf(tot * (1.f / 2048.f) + 1e-5f);
  #pragma unroll
  for (int q = 0; q < 2; ++q) {
    int j = tid * 4 + q * 1024;
    f4 wn = *(const f4*)(nw + j);
    u16x4 o = { f2bf(g[q * 4 + 0] * scale * wn[0]),
                f2bf(g[q * 4 + 1] * scale * wn[1]),
                f2bf(g[q * 4 + 2] * scale * wn[2]),
                f2bf(g[q * 4 + 3] * scale * wn[3]) };
    *(u16x4*)(gn + (size_t)r * D_INNERc + j) = o;
  }
}

// ---------------- workspace layout (bytes) ----------------
#define Z_OFF      0ull                     // zxbcdt f32 [4096][4256]  = 69,730,304
#define XB_OFF     69730304ull              // x bf16 [4096][1024]      =  8,388,608
#define WTIN_OFF   78118912ull              // W_in^T bf16 [4256][1024] =  8,716,288
#define WTOUT_OFF  86835200ull              // W_out^T bf16 [1024][2048]=  4,194,304
#define DTDEC_OFF  91029504ull              // f32 [131072][2]          =  1,048,576
#define CS_OFF     92078080ull              // f32 [131072][16][2]      = 16,777,216
#define YOUT_OFF   108855296ull             // f32 [4096][2048]         = 33,554,432
#define GN_OFF     142409728ull             // bf16 [4096][2048]        = 16,777,216
#define WT32_OFF   159186944ull             // f32 [160][1024]          =    655,360
// total 159,842,304 bytes

extern "C" void kernel_launch(void* const* d_in, const int* in_sizes, int n_in,
                              void* d_out, int out_size, void* d_ws, size_t ws_size,
                              hipStream_t stream) {
  (void)in_sizes; (void)n_in; (void)out_size; (void)ws_size;
  const float* x        = (const float*)d_in[0];
  const float* W_in     = (const float*)d_in[1];
  const float* W_out    = (const float*)d_in[2];
  const float* dt_bias  = (const float*)d_in[3];
  const float* A_log    = (const float*)d_in[4];
  const float* D_skip   = (const float*)d_in[5];
  const float* norm_w   = (const float*)d_in[6];

  char* ws = (char*)d_ws;
  float* zx              = (float*)(ws + Z_OFF);
  unsigned short* xb     = (unsigned short*)(ws + XB_OFF);
  unsigned short* wtin   = (unsigned short*)(ws + WTIN_OFF);
  unsigned short* wtout  = (unsigned short*)(ws + WTOUT_OFF);
  float* dtdec           = (float*)(ws + DTDEC_OFF);
  float* cstab           = (float*)(ws + CS_OFF);
  float* yout            = (float*)(ws + YOUT_OFF);
  unsigned short* gn     = (unsigned short*)(ws + GN_OFF);
  float* wt32            = (float*)(ws + WT32_OFF);
  float* out             = (float*)d_out;

  // zero the atomic accumulation target (ws is poisoned each launch)
  hipMemsetAsync(yout, 0, (size_t)ROWSc * D_INNERc * sizeof(float), stream);

  // convert x -> bf16
  cvt_bf16_kernel<<<4096, 256, 0, stream>>>(x, xb, (ROWSc * D_MODELc) / 4);
  // W_in [1024][4256] -> [4256][1024] bf16 (only first 4096 rows used by gemm1 now)
  transpose_to_bf16<<<dim3(133, 32), dim3(32, 8), 0, stream>>>(W_in, wtin, 1024, 4256);
  // W_out [2048][1024] -> [1024][2048] bf16
  transpose_to_bf16<<<dim3(32, 64), dim3(32, 8), 0, stream>>>(W_out, wtout, 2048, 1024);
  // BCdt weight block -> f32 [160][1024]
  transpose_bcdt_f32<<<(BCDTc * D_MODELc) / 256, 256, 0, stream>>>(W_in, wt32);

  // zxbcdt z/x columns (0..4095) via bf16 MFMA GEMM
  gemm_bf16_bt<<<dim3(ROWSc / BMt, 32), 256, 0, stream>>>(
      xb, wtin, zx, ROWSc, NPROJc, D_MODELc);

  // B/C/dt columns (4096..4255) in exact fp32 — decay chain amplifies dt error
  // by a=exp(A_log) up to 16x, so these 160 cols must not go through bf16.
  gemm_f32_bcdt<<<dim3(ROWSc / 8, BCDTc / 32), 256, 0, stream>>>(x, wt32, zx);

  // dt/decay/cos/sin tables
  prep_kernel<<<(BSZc * LSEQc * NHEADSc) / 256, 256, 0, stream>>>(zx, dt_bias, A_log, dtdec, cstab);

  // sequential state scan + D_skip
  scan_kernel<<<BSZc * NHEADSc, 256, 0, stream>>>(zx, dtdec, cstab, D_skip, yout);

  // silu gate + RMSNorm -> bf16
  epilogue_kernel<<<ROWSc, 256, 0, stream>>>(yout, zx, norm_w, gn);

  // out = gn @ W_out
  gemm_bf16_bt<<<dim3(ROWSc / BMt, D_MODELc / BNt), 256, 0, stream>>>(
      gn, wtout, out, ROWSc, D_MODELc, D_INNERc);
}

// Round 9
// 2745.666 us; speedup vs baseline: 1.0184x; 1.0184x over previous
//
#include <hip/hip_runtime.h>
#include <hip/hip_bf16.h>

// ---- problem constants ----
#define D_MODELc 1024
#define D_INNERc 2048
#define NHEADSc  32
#define LSEQc    2048
#define BSZc     2
#define NPROJc   4256   // 2*D_INNER + 2*64 + 32
#define PAIRSc   16
#define ROWSc    (BSZc*LSEQc)   // 4096
#define BCDTc    160            // B(64) + C(64) + dt(32) columns
#define CHUNKc   64             // scan steps per LDS->global dump

typedef __attribute__((ext_vector_type(4))) float f4;
typedef __attribute__((ext_vector_type(2))) float f2;
typedef __attribute__((ext_vector_type(8))) short s16x8;
typedef __attribute__((ext_vector_type(4))) float f32x4;
typedef __attribute__((ext_vector_type(4))) unsigned int u32x4;
typedef __attribute__((ext_vector_type(4))) unsigned short u16x4;

static __device__ __forceinline__ unsigned short f2bf(float f) {
  unsigned u = __float_as_uint(f);
  unsigned r = (u + 0x7fffu + ((u >> 16) & 1u)) >> 16;
  return (unsigned short)r;
}

// ---------------- convert f32 -> bf16 (vectorized) ----------------
__global__ void cvt_bf16_kernel(const float* __restrict__ in, unsigned short* __restrict__ out, int n4) {
  int i = blockIdx.x * blockDim.x + threadIdx.x;
  if (i < n4) {
    f4 v = *(const f4*)(in + (size_t)i * 4);
    u16x4 o = { f2bf(v[0]), f2bf(v[1]), f2bf(v[2]), f2bf(v[3]) };
    *(u16x4*)(out + (size_t)i * 4) = o;
  }
}

// ---------------- transpose f32 [R][C] -> bf16 [C][R] ----------------
__global__ void transpose_to_bf16(const float* __restrict__ in, unsigned short* __restrict__ out,
                                  int R, int C) {
  __shared__ float t[32][33];
  int c0 = blockIdx.x * 32, r0 = blockIdx.y * 32;
  int tx = threadIdx.x, ty = threadIdx.y; // block (32,8)
  #pragma unroll
  for (int i = 0; i < 32; i += 8)
    t[ty + i][tx] = in[(size_t)(r0 + ty + i) * C + c0 + tx];
  __syncthreads();
  #pragma unroll
  for (int i = 0; i < 32; i += 8)
    out[(size_t)(c0 + ty + i) * R + r0 + tx] = f2bf(t[tx][ty + i]);
}

// ---------------- transpose BCdt weight block to f32 [160][1024] ----------------
__global__ void transpose_bcdt_f32(const float* __restrict__ W, float* __restrict__ wt) {
  int idx = blockIdx.x * 256 + threadIdx.x;    // 160*1024 = 163840
  int j = idx >> 10, k = idx & 1023;           // wt[j][k] = W[k][4096+j]
  wt[idx] = W[(size_t)k * NPROJc + 2 * D_INNERc + j];
}

// ---------------- exact fp32 GEMM for B/C/dt columns ----------------
// zx[r][4096+j] = sum_k x[r][k] * wt[j][k]   (r<4096, j<160)
__global__ __launch_bounds__(256) void gemm_f32_bcdt(
    const float* __restrict__ x, const float* __restrict__ wt,
    float* __restrict__ zx) {
  int tid = threadIdx.x;
  int r = blockIdx.x * 8 + (tid >> 5);
  int j = blockIdx.y * 32 + (tid & 31);
  const f4* xr = (const f4*)(x + (size_t)r * D_MODELc);
  const f4* wr = (const f4*)(wt + (size_t)j * D_MODELc);
  float acc = 0.f;
  #pragma unroll 8
  for (int k = 0; k < D_MODELc / 4; ++k) {
    f4 a = xr[k], b = wr[k];
    acc = fmaf(a[0], b[0], acc);
    acc = fmaf(a[1], b[1], acc);
    acc = fmaf(a[2], b[2], acc);
    acc = fmaf(a[3], b[3], acc);
  }
  zx[(size_t)r * NPROJc + 2 * D_INNERc + j] = acc;
}

// ---------------- bf16 MFMA GEMM:  C[M][N] = A[M][K] * Bt[N][K]^T ----------------
#define BMt 128
#define BNt 128
#define BKt 64
__global__ __launch_bounds__(256) void gemm_bf16_bt(
    const unsigned short* __restrict__ A,   // [M][K] bf16 bits
    const unsigned short* __restrict__ Bt,  // [N][K] bf16 bits
    float* __restrict__ C,                  // [M][N] f32 (row stride = N)
    int M, int N, int K) {
  __shared__ unsigned short sA[BMt * BKt];
  __shared__ unsigned short sB[BNt * BKt];
  int tid = threadIdx.x;
  int lane = tid & 63;
  int wave = tid >> 6;
  int bm = blockIdx.x * BMt;
  int bn = blockIdx.y * BNt;
  int wr = (wave >> 1) * 64;
  int wc = (wave & 1) * 64;
  f32x4 acc[4][4];
  #pragma unroll
  for (int i = 0; i < 4; ++i)
    #pragma unroll
    for (int j = 0; j < 4; ++j) acc[i][j] = (f32x4){0.f, 0.f, 0.f, 0.f};
  int lr = lane & 15, lg = lane >> 4;
  for (int k0 = 0; k0 < K; k0 += BKt) {
    __syncthreads();
    #pragma unroll
    for (int q = 0; q < 4; ++q) {
      int c = tid + 256 * q;           // 0..1023: 128 rows x 8 chunks of 8 bf16
      int r = c >> 3, ch = c & 7;
      int sw = ch ^ (r & 7);           // XOR swizzle kills stride-128B bank conflict
      u32x4 va = *(const u32x4*)(A + (size_t)(bm + r) * K + k0 + ch * 8);
      *(u32x4*)(sA + r * BKt + sw * 8) = va;
      u32x4 vb = (u32x4){0u, 0u, 0u, 0u};
      if (bn + r < N) vb = *(const u32x4*)(Bt + (size_t)(bn + r) * K + k0 + ch * 8);
      *(u32x4*)(sB + r * BKt + sw * 8) = vb;
    }
    __syncthreads();
    #pragma unroll
    for (int kk = 0; kk < BKt; kk += 32) {
      s16x8 af[4], bfr[4];
      int ch = (kk >> 3) + lg;
      #pragma unroll
      for (int i = 0; i < 4; ++i) {
        int row = wr + i * 16 + lr;
        af[i] = *(const s16x8*)(sA + row * BKt + (ch ^ (row & 7)) * 8);
        int col = wc + i * 16 + lr;
        bfr[i] = *(const s16x8*)(sB + col * BKt + (ch ^ (col & 7)) * 8);
      }
      #pragma unroll
      for (int i = 0; i < 4; ++i)
        #pragma unroll
        for (int j = 0; j < 4; ++j)
          acc[i][j] = __builtin_amdgcn_mfma_f32_16x16x32_bf16(af[i], bfr[j], acc[i][j], 0, 0, 0);
    }
  }
  // C/D layout (HW-verified): col = lane&15, row = (lane>>4)*4 + reg
  #pragma unroll
  for (int i = 0; i < 4; ++i) {
    #pragma unroll
    for (int j = 0; j < 4; ++j) {
      int col = bn + wc + j * 16 + lr;
      if (col < N) {
        #pragma unroll
        for (int r = 0; r < 4; ++r) {
          int row = bm + wr + i * 16 + lg * 4 + r;
          C[(size_t)row * N + col] = acc[i][j][r];
        }
      }
    }
  }
}

// ---------------- prep: softplus/decay + rope cos/sin tables ----------------
__global__ void prep_kernel(const float* __restrict__ zx, const float* __restrict__ dt_bias,
                            const float* __restrict__ A_log, float* __restrict__ dtdec,
                            float* __restrict__ cstab) {
  int idx = blockIdx.x * 256 + threadIdx.x;   // (b*L + l)*32 + h, 131072 total
  int h = idx & 31;
  int bl = idx >> 5;
  float raw = zx[(size_t)bl * NPROJc + (2 * D_INNERc + 128) + h] + dt_bias[h];
  // numerically stable softplus
  float dt = fmaxf(raw, 0.f) + log1pf(expf(-fabsf(raw)));
  float dec = expf(-expf(A_log[h]) * dt);
  dtdec[(size_t)idx * 2] = dt;
  dtdec[(size_t)idx * 2 + 1] = dec;
  #pragma unroll
  for (int k = 0; k < PAIRSc; ++k) {
    float invf = expf(-(float)k * 0.575646273248511f); // ln(10000)/16
    float ang = dt * invf;
    float sv, cv;
    sincosf(ang, &sv, &cv);
    cstab[((size_t)idx * PAIRSc + k) * 2] = cv;
    cstab[((size_t)idx * PAIRSc + k) * 2 + 1] = sv;
  }
}

// ---------------- sequential scan (no atomics, depth-4 prefetch) ----------------
// grid = B*H = 64 blocks, 256 threads (4 waves). lane = p. wave w owns
// rope n in [8w, 8w+8) (pairs 4w..4w+4) and plain n in [32+8w, 32+8w+8).
// Each wave accumulates its partial y into its own LDS quadrant (no conflicts,
// no global atomics -> nothing slow in the vmcnt in-order retire chain).
// Every CHUNKc steps: barrier + cooperative dump to yout (plain stores).
// Depth-4 register prefetch pipeline, pinned with sched_barrier(0) so hipcc
// cannot sink the loads back to their uses (r8 showed it does: VGPR=28).
__global__ __launch_bounds__(256, 1) void scan_kernel(
    const float* __restrict__ zx, const float* __restrict__ dtdec,
    const float* __restrict__ cstab, const float* __restrict__ Dskip,
    float* __restrict__ yout) {
  int bh = blockIdx.x;
  int b = bh >> 5, h = bh & 31;
  int tid = threadIdx.x;
  int w = __builtin_amdgcn_readfirstlane(tid >> 6);
  int p = tid & 63;
  __shared__ float ylds[4][CHUNKc][64];   // 64 KiB
  float hr[16];
  #pragma unroll
  for (int i = 0; i < 16; ++i) hr[i] = 0.f;
  float dsk = Dskip[h];
  const float* zrow = zx + (size_t)b * LSEQc * NPROJc;
  const float* ddp = dtdec + ((size_t)b * LSEQc * NHEADSc + h) * 2;
  const float* csp = cstab + (((size_t)b * LSEQc * NHEADSc + h) * PAIRSc + 4 * w) * 2;
  int xoff   = D_INNERc + h * 64 + p;
  int brope  = 2 * D_INNERc + 8 * w;
  int bplain = 2 * D_INNERc + 32 + 8 * w;
  int crope  = 2 * D_INNERc + 64 + 8 * w;
  int cplain = 2 * D_INNERc + 64 + 32 + 8 * w;
  float* ybase = yout + (size_t)b * LSEQc * D_INNERc + h * 64;

  // 4 prefetch slots
  f4 br0a, br0b, bp0a, bp0b, cr0a, cr0b, cq0a, cq0b, cv0a, cv0b; float dt0, dec0, xv0;
  f4 br1a, br1b, bp1a, bp1b, cr1a, cr1b, cq1a, cq1b, cv1a, cv1b; float dt1, dec1, xv1;
  f4 br2a, br2b, bp2a, bp2b, cr2a, cr2b, cq2a, cq2b, cv2a, cv2b; float dt2, dec2, xv2;
  f4 br3a, br3b, bp3a, bp3b, cr3a, cr3b, cq3a, cq3b, cv3a, cv3b; float dt3, dec3, xv3;

#define LOADS(SFX, T) do { \
    const float* zr_ = zrow + (size_t)(T) * NPROJc; \
    br##SFX##a = *(const f4*)(zr_ + brope);      br##SFX##b = *(const f4*)(zr_ + brope + 4); \
    bp##SFX##a = *(const f4*)(zr_ + bplain);     bp##SFX##b = *(const f4*)(zr_ + bplain + 4); \
    cr##SFX##a = *(const f4*)(zr_ + crope);      cr##SFX##b = *(const f4*)(zr_ + crope + 4); \
    cq##SFX##a = *(const f4*)(zr_ + cplain);     cq##SFX##b = *(const f4*)(zr_ + cplain + 4); \
    cv##SFX##a = *(const f4*)(csp + (size_t)(T) * (NHEADSc * PAIRSc * 2)); \
    cv##SFX##b = *(const f4*)(csp + (size_t)(T) * (NHEADSc * PAIRSc * 2) + 4); \
    f2 dd_ = *(const f2*)(ddp + (size_t)(T) * (NHEADSc * 2)); \
    dt##SFX = dd_.x; dec##SFX = dd_.y; \
    xv##SFX = zr_[xoff]; \
  } while (0)

#define STEP(SFX, T, TN) do { \
    float dec_ = dec##SFX; \
    float xv_ = xv##SFX; \
    float dxp_ = dt##SFX * xv_; \
    float yp_ = 0.f; \
    _Pragma("unroll") \
    for (int k = 0; k < 4; ++k) { \
      f4 cvv = (k < 2) ? cv##SFX##a : cv##SFX##b; \
      float c_ = cvv[(k & 1) * 2], s_ = cvv[(k & 1) * 2 + 1]; \
      float cd_ = dec_ * c_, sd_ = dec_ * s_; \
      f4 bv = (k < 2) ? br##SFX##a : br##SFX##b; \
      float b1_ = bv[(2 * k) & 3], b2_ = bv[(2 * k + 1) & 3]; \
      f4 cvC = (k < 2) ? cr##SFX##a : cr##SFX##b; \
      float c1_ = cvC[(2 * k) & 3], c2_ = cvC[(2 * k + 1) & 3]; \
      float h1_ = hr[2 * k], h2_ = hr[2 * k + 1]; \
      float n1_ = fmaf(cd_, h1_, fmaf(-sd_, h2_, b1_ * dxp_)); \
      float n2_ = fmaf(sd_, h1_, fmaf(cd_, h2_, b2_ * dxp_)); \
      hr[2 * k] = n1_; hr[2 * k + 1] = n2_; \
      yp_ = fmaf(c1_, n1_, yp_); \
      yp_ = fmaf(c2_, n2_, yp_); \
    } \
    _Pragma("unroll") \
    for (int i = 0; i < 8; ++i) { \
      f4 bv = (i < 4) ? bp##SFX##a : bp##SFX##b; \
      f4 cv_ = (i < 4) ? cq##SFX##a : cq##SFX##b; \
      float hn_ = fmaf(dec_, hr[8 + i], bv[i & 3] * dxp_); \
      hr[8 + i] = hn_; \
      yp_ = fmaf(cv_[i & 3], hn_, yp_); \
    } \
    if (w == 0) yp_ = fmaf(dsk, xv_, yp_); \
    ylds[w][(T) & (CHUNKc - 1)][p] = yp_; \
    if ((TN) < LSEQc) LOADS(SFX, TN); \
    __builtin_amdgcn_sched_barrier(0); \
  } while (0)

  LOADS(0, 0);
  LOADS(1, 1);
  LOADS(2, 2);
  LOADS(3, 3);
  for (int t0 = 0; t0 < LSEQc; t0 += CHUNKc) {
    #pragma unroll 1
    for (int tt = 0; tt < CHUNKc; tt += 4) {
      int t = t0 + tt;
      STEP(0, t,     t + 4);
      STEP(1, t + 1, t + 5);
      STEP(2, t + 2, t + 6);
      STEP(3, t + 3, t + 7);
    }
    __syncthreads();
    int sq = tid >> 6;
    #pragma unroll
    for (int i = 0; i < CHUNKc / 4; ++i) {
      int s = sq * (CHUNKc / 4) + i;
      float sum = ylds[0][s][p] + ylds[1][s][p] + ylds[2][s][p] + ylds[3][s][p];
      ybase[(size_t)(t0 + s) * D_INNERc + p] = sum;
    }
    __syncthreads();
  }
#undef LOADS
#undef STEP
}

// ---------------- fused silu-gate + RMSNorm -> bf16 ----------------
__global__ __launch_bounds__(256) void epilogue_kernel(
    const float* __restrict__ yout, const float* __restrict__ zx,
    const float* __restrict__ nw, unsigned short* __restrict__ gn) {
  int r = blockIdx.x;
  int tid = threadIdx.x;
  const float* yr = yout + (size_t)r * D_INNERc;
  const float* zr = zx + (size_t)r * NPROJc;   // z = first 2048 cols
  float g[8];
  float ss = 0.f;
  #pragma unroll
  for (int q = 0; q < 2; ++q) {
    int j = tid * 4 + q * 1024;
    f4 y = *(const f4*)(yr + j);
    f4 z = *(const f4*)(zr + j);
    #pragma unroll
    for (int e = 0; e < 4; ++e) {
      float zz = z[e];
      float sig = 1.f / (1.f + expf(-zz));
      float gg = y[e] * zz * sig;
      g[q * 4 + e] = gg;
      ss = fmaf(gg, gg, ss);
    }
  }
  #pragma unroll
  for (int o = 1; o < 64; o <<= 1) ss += __shfl_xor(ss, o);
  __shared__ float red[4];
  int wv = tid >> 6, lane = tid & 63;
  if (lane == 0) red[wv] = ss;
  __syncthreads();
  float tot = red[0] + red[1] + red[2] + red[3];
  float scale = rsqrtf(tot * (1.f / 2048.f) + 1e-5f);
  #pragma unroll
  for (int q = 0; q < 2; ++q) {
    int j = tid * 4 + q * 1024;
    f4 wn = *(const f4*)(nw + j);
    u16x4 o = { f2bf(g[q * 4 + 0] * scale * wn[0]),
                f2bf(g[q * 4 + 1] * scale * wn[1]),
                f2bf(g[q * 4 + 2] * scale * wn[2]),
                f2bf(g[q * 4 + 3] * scale * wn[3]) };
    *(u16x4*)(gn + (size_t)r * D_INNERc + j) = o;
  }
}

// ---------------- workspace layout (bytes) ----------------
#define Z_OFF      0ull                     // zxbcdt f32 [4096][4256]  = 69,730,304
#define XB_OFF     69730304ull              // x bf16 [4096][1024]      =  8,388,608
#define WTIN_OFF   78118912ull              // W_in^T bf16 [4256][1024] =  8,716,288
#define WTOUT_OFF  86835200ull              // W_out^T bf16 [1024][2048]=  4,194,304
#define DTDEC_OFF  91029504ull              // f32 [131072][2]          =  1,048,576
#define CS_OFF     92078080ull              // f32 [131072][16][2]      = 16,777,216
#define YOUT_OFF   108855296ull             // f32 [4096][2048]         = 33,554,432
#define GN_OFF     142409728ull             // bf16 [4096][2048]        = 16,777,216
#define WT32_OFF   159186944ull             // f32 [160][1024]          =    655,360
// total 159,842,304 bytes

extern "C" void kernel_launch(void* const* d_in, const int* in_sizes, int n_in,
                              void* d_out, int out_size, void* d_ws, size_t ws_size,
                              hipStream_t stream) {
  (void)in_sizes; (void)n_in; (void)out_size; (void)ws_size;
  const float* x        = (const float*)d_in[0];
  const float* W_in     = (const float*)d_in[1];
  const float* W_out    = (const float*)d_in[2];
  const float* dt_bias  = (const float*)d_in[3];
  const float* A_log    = (const float*)d_in[4];
  const float* D_skip   = (const float*)d_in[5];
  const float* norm_w   = (const float*)d_in[6];

  char* ws = (char*)d_ws;
  float* zx              = (float*)(ws + Z_OFF);
  unsigned short* xb     = (unsigned short*)(ws + XB_OFF);
  unsigned short* wtin   = (unsigned short*)(ws + WTIN_OFF);
  unsigned short* wtout  = (unsigned short*)(ws + WTOUT_OFF);
  float* dtdec           = (float*)(ws + DTDEC_OFF);
  float* cstab           = (float*)(ws + CS_OFF);
  float* yout            = (float*)(ws + YOUT_OFF);
  unsigned short* gn     = (unsigned short*)(ws + GN_OFF);
  float* wt32            = (float*)(ws + WT32_OFF);
  float* out             = (float*)d_out;

  // convert x -> bf16
  cvt_bf16_kernel<<<4096, 256, 0, stream>>>(x, xb, (ROWSc * D_MODELc) / 4);
  // W_in [1024][4256] -> [4256][1024] bf16 (only first 4096 rows used by gemm1)
  transpose_to_bf16<<<dim3(133, 32), dim3(32, 8), 0, stream>>>(W_in, wtin, 1024, 4256);
  // W_out [2048][1024] -> [1024][2048] bf16
  transpose_to_bf16<<<dim3(32, 64), dim3(32, 8), 0, stream>>>(W_out, wtout, 2048, 1024);
  // BCdt weight block -> f32 [160][1024]
  transpose_bcdt_f32<<<(BCDTc * D_MODELc) / 256, 256, 0, stream>>>(W_in, wt32);

  // zxbcdt z/x columns (0..4095) via bf16 MFMA GEMM
  gemm_bf16_bt<<<dim3(ROWSc / BMt, 32), 256, 0, stream>>>(
      xb, wtin, zx, ROWSc, NPROJc, D_MODELc);

  // B/C/dt columns (4096..4255) in exact fp32 — decay chain amplifies dt error
  // by a=exp(A_log) up to 16x, so these 160 cols must not go through bf16.
  gemm_f32_bcdt<<<dim3(ROWSc / 8, BCDTc / 32), 256, 0, stream>>>(x, wt32, zx);

  // dt/decay/cos/sin tables
  prep_kernel<<<(BSZc * LSEQc * NHEADSc) / 256, 256, 0, stream>>>(zx, dt_bias, A_log, dtdec, cstab);

  // sequential state scan + D_skip (writes every yout cell; no memset needed)
  scan_kernel<<<BSZc * NHEADSc, 256, 0, stream>>>(zx, dtdec, cstab, D_skip, yout);

  // silu gate + RMSNorm -> bf16
  epilogue_kernel<<<ROWSc, 256, 0, stream>>>(yout, zx, norm_w, gn);

  // out = gn @ W_out
  gemm_bf16_bt<<<dim3(ROWSc / BMt, D_MODELc / BNt), 256, 0, stream>>>(
      gn, wtout, out, ROWSc, D_MODELc, D_INNERc);
}

// Round 10
// 881.105 us; speedup vs baseline: 3.1734x; 3.1162x over previous
//
#include <hip/hip_runtime.h>
#include <hip/hip_bf16.h>

// ---- problem constants ----
#define D_MODELc 1024
#define D_INNERc 2048
#define NHEADSc  32
#define LSEQc    2048
#define BSZc     2
#define NPROJc   4256   // 2*D_INNER + 2*64 + 32
#define PAIRSc   16
#define ROWSc    (BSZc*LSEQc)   // 4096
#define BCDTc    160            // B(64) + C(64) + dt(32) columns
#define NCHc     32             // scan chunks
#define CLc      64             // steps per chunk

typedef __attribute__((ext_vector_type(4))) float f4;
typedef __attribute__((ext_vector_type(2))) float f2;
typedef __attribute__((ext_vector_type(8))) short s16x8;
typedef __attribute__((ext_vector_type(4))) float f32x4;
typedef __attribute__((ext_vector_type(4))) unsigned int u32x4;
typedef __attribute__((ext_vector_type(4))) unsigned short u16x4;

static __device__ __forceinline__ unsigned short f2bf(float f) {
  unsigned u = __float_as_uint(f);
  unsigned r = (u + 0x7fffu + ((u >> 16) & 1u)) >> 16;
  return (unsigned short)r;
}

// ---------------- convert f32 -> bf16 (vectorized) ----------------
__global__ void cvt_bf16_kernel(const float* __restrict__ in, unsigned short* __restrict__ out, int n4) {
  int i = blockIdx.x * blockDim.x + threadIdx.x;
  if (i < n4) {
    f4 v = *(const f4*)(in + (size_t)i * 4);
    u16x4 o = { f2bf(v[0]), f2bf(v[1]), f2bf(v[2]), f2bf(v[3]) };
    *(u16x4*)(out + (size_t)i * 4) = o;
  }
}

// ---------------- transpose f32 [R][C] -> bf16 [C][R] ----------------
__global__ void transpose_to_bf16(const float* __restrict__ in, unsigned short* __restrict__ out,
                                  int R, int C) {
  __shared__ float t[32][33];
  int c0 = blockIdx.x * 32, r0 = blockIdx.y * 32;
  int tx = threadIdx.x, ty = threadIdx.y; // block (32,8)
  #pragma unroll
  for (int i = 0; i < 32; i += 8)
    t[ty + i][tx] = in[(size_t)(r0 + ty + i) * C + c0 + tx];
  __syncthreads();
  #pragma unroll
  for (int i = 0; i < 32; i += 8)
    out[(size_t)(c0 + ty + i) * R + r0 + tx] = f2bf(t[tx][ty + i]);
}

// ---------------- transpose BCdt weight block to f32 [160][1024] ----------------
__global__ void transpose_bcdt_f32(const float* __restrict__ W, float* __restrict__ wt) {
  int idx = blockIdx.x * 256 + threadIdx.x;    // 160*1024 = 163840
  int j = idx >> 10, k = idx & 1023;           // wt[j][k] = W[k][4096+j]
  wt[idx] = W[(size_t)k * NPROJc + 2 * D_INNERc + j];
}

// ---------------- exact fp32 GEMM for B/C/dt columns ----------------
__global__ __launch_bounds__(256) void gemm_f32_bcdt(
    const float* __restrict__ x, const float* __restrict__ wt,
    float* __restrict__ zx) {
  int tid = threadIdx.x;
  int r = blockIdx.x * 8 + (tid >> 5);
  int j = blockIdx.y * 32 + (tid & 31);
  const f4* xr = (const f4*)(x + (size_t)r * D_MODELc);
  const f4* wr = (const f4*)(wt + (size_t)j * D_MODELc);
  float acc = 0.f;
  #pragma unroll 8
  for (int k = 0; k < D_MODELc / 4; ++k) {
    f4 a = xr[k], b = wr[k];
    acc = fmaf(a[0], b[0], acc);
    acc = fmaf(a[1], b[1], acc);
    acc = fmaf(a[2], b[2], acc);
    acc = fmaf(a[3], b[3], acc);
  }
  zx[(size_t)r * NPROJc + 2 * D_INNERc + j] = acc;
}

// ---------------- bf16 MFMA GEMM:  C[M][N] = A[M][K] * Bt[N][K]^T ----------------
#define BMt 128
#define BNt 128
#define BKt 64
__global__ __launch_bounds__(256) void gemm_bf16_bt(
    const unsigned short* __restrict__ A,   // [M][K] bf16 bits
    const unsigned short* __restrict__ Bt,  // [N][K] bf16 bits
    float* __restrict__ C,                  // [M][N] f32 (row stride = N)
    int M, int N, int K) {
  __shared__ unsigned short sA[BMt * BKt];
  __shared__ unsigned short sB[BNt * BKt];
  int tid = threadIdx.x;
  int lane = tid & 63;
  int wave = tid >> 6;
  int bm = blockIdx.x * BMt;
  int bn = blockIdx.y * BNt;
  int wr = (wave >> 1) * 64;
  int wc = (wave & 1) * 64;
  f32x4 acc[4][4];
  #pragma unroll
  for (int i = 0; i < 4; ++i)
    #pragma unroll
    for (int j = 0; j < 4; ++j) acc[i][j] = (f32x4){0.f, 0.f, 0.f, 0.f};
  int lr = lane & 15, lg = lane >> 4;
  for (int k0 = 0; k0 < K; k0 += BKt) {
    __syncthreads();
    #pragma unroll
    for (int q = 0; q < 4; ++q) {
      int c = tid + 256 * q;           // 0..1023: 128 rows x 8 chunks of 8 bf16
      int r = c >> 3, ch = c & 7;
      int sw = ch ^ (r & 7);           // XOR swizzle kills stride-128B bank conflict
      u32x4 va = *(const u32x4*)(A + (size_t)(bm + r) * K + k0 + ch * 8);
      *(u32x4*)(sA + r * BKt + sw * 8) = va;
      u32x4 vb = (u32x4){0u, 0u, 0u, 0u};
      if (bn + r < N) vb = *(const u32x4*)(Bt + (size_t)(bn + r) * K + k0 + ch * 8);
      *(u32x4*)(sB + r * BKt + sw * 8) = vb;
    }
    __syncthreads();
    #pragma unroll
    for (int kk = 0; kk < BKt; kk += 32) {
      s16x8 af[4], bfr[4];
      int ch = (kk >> 3) + lg;
      #pragma unroll
      for (int i = 0; i < 4; ++i) {
        int row = wr + i * 16 + lr;
        af[i] = *(const s16x8*)(sA + row * BKt + (ch ^ (row & 7)) * 8);
        int col = wc + i * 16 + lr;
        bfr[i] = *(const s16x8*)(sB + col * BKt + (ch ^ (col & 7)) * 8);
      }
      #pragma unroll
      for (int i = 0; i < 4; ++i)
        #pragma unroll
        for (int j = 0; j < 4; ++j)
          acc[i][j] = __builtin_amdgcn_mfma_f32_16x16x32_bf16(af[i], bfr[j], acc[i][j], 0, 0, 0);
    }
  }
  // C/D layout (HW-verified): col = lane&15, row = (lane>>4)*4 + reg
  #pragma unroll
  for (int i = 0; i < 4; ++i) {
    #pragma unroll
    for (int j = 0; j < 4; ++j) {
      int col = bn + wc + j * 16 + lr;
      if (col < N) {
        #pragma unroll
        for (int r = 0; r < 4; ++r) {
          int row = bm + wr + i * 16 + lg * 4 + r;
          C[(size_t)row * N + col] = acc[i][j][r];
        }
      }
    }
  }
}

// ---------------- prep: softplus/decay + rope cos/sin tables ----------------
__global__ void prep_kernel(const float* __restrict__ zx, const float* __restrict__ dt_bias,
                            const float* __restrict__ A_log, float* __restrict__ dtdec,
                            float* __restrict__ cstab) {
  int idx = blockIdx.x * 256 + threadIdx.x;   // (b*L + l)*32 + h, 131072 total
  int h = idx & 31;
  int bl = idx >> 5;
  float raw = zx[(size_t)bl * NPROJc + (2 * D_INNERc + 128) + h] + dt_bias[h];
  float dt = fmaxf(raw, 0.f) + log1pf(expf(-fabsf(raw)));
  float dec = expf(-expf(A_log[h]) * dt);
  dtdec[(size_t)idx * 2] = dt;
  dtdec[(size_t)idx * 2 + 1] = dec;
  #pragma unroll
  for (int k = 0; k < PAIRSc; ++k) {
    float invf = expf(-(float)k * 0.575646273248511f); // ln(10000)/16
    float ang = dt * invf;
    float sv, cv;
    sincosf(ang, &sv, &cv);
    cstab[((size_t)idx * PAIRSc + k) * 2] = cv;
    cstab[((size_t)idx * PAIRSc + k) * 2 + 1] = sv;
  }
}

// ================= chunk-parallel scan =================
// Chunk transition for head h composes to: h_end = P * R(S*invf_k) * h_start + f
// with S = sum(dt), P = prod(dec) over the chunk (dec scalar per (t,h); all pair
// rotations commute). Phase 1: local scans from 0 (2048 blocks, full TLP).
// Phase 2: cheap 32-step sequential composition per (b,h). Phase 3: re-run
// chunks with corrected h_start, emitting y (2048 blocks).

// ---- phase 1: local chunk scan from zero state; writes f_c and (S,P) ----
__global__ __launch_bounds__(256) void scan_local(
    const float* __restrict__ zx, const float* __restrict__ dtdec,
    const float* __restrict__ cstab, float* __restrict__ fbuf,
    float* __restrict__ agg) {
  int bid = blockIdx.x;
  int bh = bid >> 5, c = bid & 31;
  int b = bh >> 5, h = bh & 31;
  int tid = threadIdx.x;
  int w = tid >> 6;
  int p = tid & 63;
  float hr[16];
  #pragma unroll
  for (int i = 0; i < 16; ++i) hr[i] = 0.f;
  float sdt = 0.f, pdec = 1.f;
  const float* zrow = zx + (size_t)b * LSEQc * NPROJc;
  const float* ddp = dtdec + ((size_t)b * LSEQc * NHEADSc + h) * 2;
  const float* csp = cstab + (((size_t)b * LSEQc * NHEADSc + h) * PAIRSc + 4 * w) * 2;
  int xoff   = D_INNERc + h * 64 + p;
  int brope  = 2 * D_INNERc + 8 * w;
  int bplain = 2 * D_INNERc + 32 + 8 * w;
  int t0 = c * CLc;
  for (int s = 0; s < CLc; ++s) {
    int t = t0 + s;
    const float* zr = zrow + (size_t)t * NPROJc;
    f4 bra = *(const f4*)(zr + brope),  brb = *(const f4*)(zr + brope + 4);
    f4 bpa = *(const f4*)(zr + bplain), bpb = *(const f4*)(zr + bplain + 4);
    f4 cva = *(const f4*)(csp + (size_t)t * (NHEADSc * PAIRSc * 2));
    f4 cvb = *(const f4*)(csp + (size_t)t * (NHEADSc * PAIRSc * 2) + 4);
    f2 dd = *(const f2*)(ddp + (size_t)t * (NHEADSc * 2));
    float dt = dd.x, dec = dd.y;
    float xv = zr[xoff];
    float dxp = dt * xv;
    #pragma unroll
    for (int k = 0; k < 4; ++k) {
      f4 cvv = (k < 2) ? cva : cvb;
      float cc = cvv[(k & 1) * 2], ss = cvv[(k & 1) * 2 + 1];
      float cd = dec * cc, sd = dec * ss;
      f4 bv = (k < 2) ? bra : brb;
      float b1 = bv[(2 * k) & 3], b2 = bv[(2 * k + 1) & 3];
      float h1 = hr[2 * k], h2 = hr[2 * k + 1];
      hr[2 * k]     = fmaf(cd, h1, fmaf(-sd, h2, b1 * dxp));
      hr[2 * k + 1] = fmaf(sd, h1, fmaf(cd, h2, b2 * dxp));
    }
    #pragma unroll
    for (int i = 0; i < 8; ++i) {
      f4 bv = (i < 4) ? bpa : bpb;
      hr[8 + i] = fmaf(dec, hr[8 + i], bv[i & 3] * dxp);
    }
    sdt += dt;
    pdec *= dec;
  }
  float* fslot = fbuf + (size_t)(bh * NCHc + c) * (64 * 64);
  #pragma unroll
  for (int i = 0; i < 8; ++i) {
    fslot[(8 * w + i) * 64 + p]      = hr[i];
    fslot[(32 + 8 * w + i) * 64 + p] = hr[8 + i];
  }
  if (tid == 0) {
    agg[(bh * NCHc + c) * 2]     = sdt;
    agg[(bh * NCHc + c) * 2 + 1] = pdec;
  }
}

// ---- phase 2: sequential composition; h_start(c) written into slot c-1 ----
__global__ __launch_bounds__(256) void scan_phase2(
    float* __restrict__ fbuf, const float* __restrict__ agg) {
  int bh = blockIdx.x;
  int tid = threadIdx.x;
  int w = tid >> 6;
  int p = tid & 63;
  float hr[16];
  #pragma unroll
  for (int i = 0; i < 16; ++i) hr[i] = 0.f;
  float invfk[4];
  #pragma unroll
  for (int kk = 0; kk < 4; ++kk)
    invfk[kk] = expf(-(float)(4 * w + kk) * 0.575646273248511f);
  for (int c = 1; c < NCHc; ++c) {
    f2 ag = *(const f2*)(agg + (size_t)(bh * NCHc + c - 1) * 2);
    float sdt = ag.x, pd = ag.y;
    float* fslot = fbuf + (size_t)(bh * NCHc + c - 1) * (64 * 64);
    // h_start(c) = P*R(S)*h_start(c-1) + f_{c-1}
    #pragma unroll
    for (int kk = 0; kk < 4; ++kk) {
      float th = sdt * invfk[kk];
      float sn, cs_;
      __sincosf(th, &sn, &cs_);   // fast path ok: |angle err| ~1e-6 rad
      float cdp = pd * cs_, sdp = pd * sn;
      int n1 = 8 * w + 2 * kk;
      float f1 = fslot[n1 * 64 + p], f2v = fslot[(n1 + 1) * 64 + p];
      float h1 = hr[2 * kk], h2 = hr[2 * kk + 1];
      hr[2 * kk]     = fmaf(cdp, h1, fmaf(-sdp, h2, f1));
      hr[2 * kk + 1] = fmaf(sdp, h1, fmaf(cdp, h2, f2v));
    }
    #pragma unroll
    for (int i = 0; i < 8; ++i) {
      int n = 32 + 8 * w + i;
      hr[8 + i] = fmaf(pd, hr[8 + i], fslot[n * 64 + p]);
    }
    // overwrite consumed slot with h_start(c)
    #pragma unroll
    for (int i = 0; i < 8; ++i) {
      fslot[(8 * w + i) * 64 + p]      = hr[i];
      fslot[(32 + 8 * w + i) * 64 + p] = hr[8 + i];
    }
  }
}

// ---- phase 3: re-run chunk with corrected h_start, emit y ----
__global__ __launch_bounds__(256) void scan_fix(
    const float* __restrict__ zx, const float* __restrict__ dtdec,
    const float* __restrict__ cstab, const float* __restrict__ Dskip,
    const float* __restrict__ fbuf, float* __restrict__ yout) {
  int bid = blockIdx.x;
  int bh = bid >> 5, c = bid & 31;
  int b = bh >> 5, h = bh & 31;
  int tid = threadIdx.x;
  int w = tid >> 6;
  int p = tid & 63;
  __shared__ float ylds[4][32][64];   // 32 KiB
  float hr[16];
  if (c == 0) {
    #pragma unroll
    for (int i = 0; i < 16; ++i) hr[i] = 0.f;
  } else {
    const float* fslot = fbuf + (size_t)(bh * NCHc + c - 1) * (64 * 64);
    #pragma unroll
    for (int i = 0; i < 8; ++i) {
      hr[i]     = fslot[(8 * w + i) * 64 + p];
      hr[8 + i] = fslot[(32 + 8 * w + i) * 64 + p];
    }
  }
  float dsk = Dskip[h];
  const float* zrow = zx + (size_t)b * LSEQc * NPROJc;
  const float* ddp = dtdec + ((size_t)b * LSEQc * NHEADSc + h) * 2;
  const float* csp = cstab + (((size_t)b * LSEQc * NHEADSc + h) * PAIRSc + 4 * w) * 2;
  int xoff   = D_INNERc + h * 64 + p;
  int brope  = 2 * D_INNERc + 8 * w;
  int bplain = 2 * D_INNERc + 32 + 8 * w;
  int crope  = 2 * D_INNERc + 64 + 8 * w;
  int cplain = 2 * D_INNERc + 64 + 32 + 8 * w;
  float* ybase = yout + (size_t)b * LSEQc * D_INNERc + h * 64 + p;
  int t0c = c * CLc;
  #pragma unroll 1
  for (int half = 0; half < 2; ++half) {
    int tb = t0c + half * 32;
    #pragma unroll 1
    for (int s = 0; s < 32; ++s) {
      int t = tb + s;
      const float* zr = zrow + (size_t)t * NPROJc;
      f4 bra = *(const f4*)(zr + brope),  brb = *(const f4*)(zr + brope + 4);
      f4 bpa = *(const f4*)(zr + bplain), bpb = *(const f4*)(zr + bplain + 4);
      f4 cra = *(const f4*)(zr + crope),  crb = *(const f4*)(zr + crope + 4);
      f4 cqa = *(const f4*)(zr + cplain), cqb = *(const f4*)(zr + cplain + 4);
      f4 cva = *(const f4*)(csp + (size_t)t * (NHEADSc * PAIRSc * 2));
      f4 cvb = *(const f4*)(csp + (size_t)t * (NHEADSc * PAIRSc * 2) + 4);
      f2 dd = *(const f2*)(ddp + (size_t)t * (NHEADSc * 2));
      float dt = dd.x, dec = dd.y;
      float xv = zr[xoff];
      float dxp = dt * xv;
      float yp = 0.f;
      #pragma unroll
      for (int k = 0; k < 4; ++k) {
        f4 cvv = (k < 2) ? cva : cvb;
        float cc = cvv[(k & 1) * 2], ss = cvv[(k & 1) * 2 + 1];
        float cd = dec * cc, sd = dec * ss;
        f4 bv = (k < 2) ? bra : brb;
        float b1 = bv[(2 * k) & 3], b2 = bv[(2 * k + 1) & 3];
        f4 cvC = (k < 2) ? cra : crb;
        float c1 = cvC[(2 * k) & 3], c2 = cvC[(2 * k + 1) & 3];
        float h1 = hr[2 * k], h2 = hr[2 * k + 1];
        float n1 = fmaf(cd, h1, fmaf(-sd, h2, b1 * dxp));
        float n2 = fmaf(sd, h1, fmaf(cd, h2, b2 * dxp));
        hr[2 * k] = n1; hr[2 * k + 1] = n2;
        yp = fmaf(c1, n1, yp);
        yp = fmaf(c2, n2, yp);
      }
      #pragma unroll
      for (int i = 0; i < 8; ++i) {
        f4 bv = (i < 4) ? bpa : bpb;
        f4 cv = (i < 4) ? cqa : cqb;
        float hn = fmaf(dec, hr[8 + i], bv[i & 3] * dxp);
        hr[8 + i] = hn;
        yp = fmaf(cv[i & 3], hn, yp);
      }
      if (w == 0) yp = fmaf(dsk, xv, yp);
      ylds[w][s][p] = yp;
    }
    __syncthreads();
    int sq = tid >> 6;
    #pragma unroll
    for (int i = 0; i < 8; ++i) {
      int s = sq * 8 + i;
      float sum = ylds[0][s][p] + ylds[1][s][p] + ylds[2][s][p] + ylds[3][s][p];
      ybase[(size_t)(tb + s) * D_INNERc] = sum;
    }
    __syncthreads();
  }
}

// ---------------- fused silu-gate + RMSNorm -> bf16 ----------------
__global__ __launch_bounds__(256) void epilogue_kernel(
    const float* __restrict__ yout, const float* __restrict__ zx,
    const float* __restrict__ nw, unsigned short* __restrict__ gn) {
  int r = blockIdx.x;
  int tid = threadIdx.x;
  const float* yr = yout + (size_t)r * D_INNERc;
  const float* zr = zx + (size_t)r * NPROJc;   // z = first 2048 cols
  float g[8];
  float ss = 0.f;
  #pragma unroll
  for (int q = 0; q < 2; ++q) {
    int j = tid * 4 + q * 1024;
    f4 y = *(const f4*)(yr + j);
    f4 z = *(const f4*)(zr + j);
    #pragma unroll
    for (int e = 0; e < 4; ++e) {
      float zz = z[e];
      float sig = 1.f / (1.f + expf(-zz));
      float gg = y[e] * zz * sig;
      g[q * 4 + e] = gg;
      ss = fmaf(gg, gg, ss);
    }
  }
  #pragma unroll
  for (int o = 1; o < 64; o <<= 1) ss += __shfl_xor(ss, o);
  __shared__ float red[4];
  int wv = tid >> 6, lane = tid & 63;
  if (lane == 0) red[wv] = ss;
  __syncthreads();
  float tot = red[0] + red[1] + red[2] + red[3];
  float scale = rsqrtf(tot * (1.f / 2048.f) + 1e-5f);
  #pragma unroll
  for (int q = 0; q < 2; ++q) {
    int j = tid * 4 + q * 1024;
    f4 wn = *(const f4*)(nw + j);
    u16x4 o = { f2bf(g[q * 4 + 0] * scale * wn[0]),
                f2bf(g[q * 4 + 1] * scale * wn[1]),
                f2bf(g[q * 4 + 2] * scale * wn[2]),
                f2bf(g[q * 4 + 3] * scale * wn[3]) };
    *(u16x4*)(gn + (size_t)r * D_INNERc + j) = o;
  }
}

// ---------------- workspace layout (bytes) ----------------
#define Z_OFF      0ull                     // zxbcdt f32 [4096][4256]  = 69,730,304
#define XB_OFF     69730304ull              // x bf16 [4096][1024]      =  8,388,608
#define WTIN_OFF   78118912ull              // W_in^T bf16 [4256][1024] =  8,716,288
#define WTOUT_OFF  86835200ull              // W_out^T bf16 [1024][2048]=  4,194,304
#define DTDEC_OFF  91029504ull              // f32 [131072][2]          =  1,048,576
#define CS_OFF     92078080ull              // f32 [131072][16][2]      = 16,777,216
#define YOUT_OFF   108855296ull             // f32 [4096][2048]         = 33,554,432
#define GN_OFF     142409728ull             // bf16 [4096][2048]        = 16,777,216
#define WT32_OFF   159186944ull             // f32 [160][1024]          =    655,360
#define FB_OFF     159842304ull             // f32 [64][32][64][64]     = 33,554,432
#define AGG_OFF    193396736ull             // f32 [64][32][2]          =     16,384
// total 193,413,120 bytes

extern "C" void kernel_launch(void* const* d_in, const int* in_sizes, int n_in,
                              void* d_out, int out_size, void* d_ws, size_t ws_size,
                              hipStream_t stream) {
  (void)in_sizes; (void)n_in; (void)out_size; (void)ws_size;
  const float* x        = (const float*)d_in[0];
  const float* W_in     = (const float*)d_in[1];
  const float* W_out    = (const float*)d_in[2];
  const float* dt_bias  = (const float*)d_in[3];
  const float* A_log    = (const float*)d_in[4];
  const float* D_skip   = (const float*)d_in[5];
  const float* norm_w   = (const float*)d_in[6];

  char* ws = (char*)d_ws;
  float* zx              = (float*)(ws + Z_OFF);
  unsigned short* xb     = (unsigned short*)(ws + XB_OFF);
  unsigned short* wtin   = (unsigned short*)(ws + WTIN_OFF);
  unsigned short* wtout  = (unsigned short*)(ws + WTOUT_OFF);
  float* dtdec           = (float*)(ws + DTDEC_OFF);
  float* cstab           = (float*)(ws + CS_OFF);
  float* yout            = (float*)(ws + YOUT_OFF);
  unsigned short* gn     = (unsigned short*)(ws + GN_OFF);
  float* wt32            = (float*)(ws + WT32_OFF);
  float* fbuf            = (float*)(ws + FB_OFF);
  float* agg             = (float*)(ws + AGG_OFF);
  float* out             = (float*)d_out;

  // convert x -> bf16
  cvt_bf16_kernel<<<4096, 256, 0, stream>>>(x, xb, (ROWSc * D_MODELc) / 4);
  // W_in [1024][4256] -> [4256][1024] bf16 (first 4096 rows used by gemm1)
  transpose_to_bf16<<<dim3(133, 32), dim3(32, 8), 0, stream>>>(W_in, wtin, 1024, 4256);
  // W_out [2048][1024] -> [1024][2048] bf16
  transpose_to_bf16<<<dim3(32, 64), dim3(32, 8), 0, stream>>>(W_out, wtout, 2048, 1024);
  // BCdt weight block -> f32 [160][1024]
  transpose_bcdt_f32<<<(BCDTc * D_MODELc) / 256, 256, 0, stream>>>(W_in, wt32);

  // zxbcdt z/x columns (0..4095) via bf16 MFMA GEMM
  gemm_bf16_bt<<<dim3(ROWSc / BMt, 32), 256, 0, stream>>>(
      xb, wtin, zx, ROWSc, NPROJc, D_MODELc);

  // B/C/dt columns (4096..4255) in exact fp32 (decay chain amplifies dt error)
  gemm_f32_bcdt<<<dim3(ROWSc / 8, BCDTc / 32), 256, 0, stream>>>(x, wt32, zx);

  // dt/decay/cos/sin tables
  prep_kernel<<<(BSZc * LSEQc * NHEADSc) / 256, 256, 0, stream>>>(zx, dt_bias, A_log, dtdec, cstab);

  // chunk-parallel scan: local scans -> sequential composition -> fix-up
  scan_local<<<BSZc * NHEADSc * NCHc, 256, 0, stream>>>(zx, dtdec, cstab, fbuf, agg);
  scan_phase2<<<BSZc * NHEADSc, 256, 0, stream>>>(fbuf, agg);
  scan_fix<<<BSZc * NHEADSc * NCHc, 256, 0, stream>>>(zx, dtdec, cstab, D_skip, fbuf, yout);

  // silu gate + RMSNorm -> bf16
  epilogue_kernel<<<ROWSc, 256, 0, stream>>>(yout, zx, norm_w, gn);

  // out = gn @ W_out
  gemm_bf16_bt<<<dim3(ROWSc / BMt, D_MODELc / BNt), 256, 0, stream>>>(
      gn, wtout, out, ROWSc, D_MODELc, D_INNERc);
}

// Round 13
// 575.162 us; speedup vs baseline: 4.8615x; 1.5319x over previous
//
#include <hip/hip_runtime.h>
#include <hip/hip_bf16.h>

// ---- problem constants ----
#define D_MODELc 1024
#define D_INNERc 2048
#define NHEADSc  32
#define LSEQc    2048
#define BSZc     2
#define NPROJc   4256   // 2*D_INNER + 2*64 + 32
#define PAIRSc   16
#define ROWSc    (BSZc*LSEQc)   // 4096
#define BCDTc    160            // B(64) + C(64) + dt(32) columns
#define NCHc     32             // scan chunks
#define CLc      64             // steps per chunk

typedef __attribute__((ext_vector_type(4))) float f4;
typedef __attribute__((ext_vector_type(2))) float f2;
typedef __attribute__((ext_vector_type(8))) short s16x8;
typedef __attribute__((ext_vector_type(4))) float f32x4;
typedef __attribute__((ext_vector_type(4))) unsigned int u32x4;
typedef __attribute__((ext_vector_type(4))) unsigned short u16x4;

static __device__ __forceinline__ unsigned short f2bf(float f) {
  unsigned u = __float_as_uint(f);
  unsigned r = (u + 0x7fffu + ((u >> 16) & 1u)) >> 16;
  return (unsigned short)r;
}

// ---------------- convert f32 -> bf16 hi + lo (split precision) ----------------
__global__ void cvt_bf16_split(const float* __restrict__ in, unsigned short* __restrict__ hi,
                               unsigned short* __restrict__ lo, int n4) {
  int i = blockIdx.x * blockDim.x + threadIdx.x;
  if (i < n4) {
    f4 v = *(const f4*)(in + (size_t)i * 4);
    u16x4 oh, ol;
    #pragma unroll
    for (int e = 0; e < 4; ++e) {
      unsigned short hb = f2bf(v[e]);
      float hf = __uint_as_float((unsigned)hb << 16);
      oh[e] = hb;
      ol[e] = f2bf(v[e] - hf);
    }
    *(u16x4*)(hi + (size_t)i * 4) = oh;
    *(u16x4*)(lo + (size_t)i * 4) = ol;
  }
}

// ---------------- transpose f32 [R][C] -> bf16 [C][R] ----------------
__global__ void transpose_to_bf16(const float* __restrict__ in, unsigned short* __restrict__ out,
                                  int R, int C) {
  __shared__ float t[32][33];
  int c0 = blockIdx.x * 32, r0 = blockIdx.y * 32;
  int tx = threadIdx.x, ty = threadIdx.y; // block (32,8)
  #pragma unroll
  for (int i = 0; i < 32; i += 8)
    t[ty + i][tx] = in[(size_t)(r0 + ty + i) * C + c0 + tx];
  __syncthreads();
  #pragma unroll
  for (int i = 0; i < 32; i += 8)
    out[(size_t)(c0 + ty + i) * R + r0 + tx] = f2bf(t[tx][ty + i]);
}

// ---------------- transpose BCdt weight block -> bf16 hi/lo [160][1024] ----------------
__global__ void transpose_wb_bf16(const float* __restrict__ W,
                                  unsigned short* __restrict__ bh,
                                  unsigned short* __restrict__ bl) {
  __shared__ float t[32][33];
  int c0 = blockIdx.x * 32;   // j tile (5)
  int r0 = blockIdx.y * 32;   // k tile (32)
  int tx = threadIdx.x, ty = threadIdx.y; // block (32,8)
  #pragma unroll
  for (int i = 0; i < 32; i += 8)
    t[ty + i][tx] = W[(size_t)(r0 + ty + i) * NPROJc + 2 * D_INNERc + c0 + tx];
  __syncthreads();
  #pragma unroll
  for (int i = 0; i < 32; i += 8) {
    float v = t[tx][ty + i];
    unsigned short hb = f2bf(v);
    float hf = __uint_as_float((unsigned)hb << 16);
    size_t o = (size_t)(c0 + ty + i) * D_MODELc + r0 + tx;
    bh[o] = hb;
    bl[o] = f2bf(v - hf);
  }
}

// ---------------- bf16 MFMA GEMM:  C[M][N] = A[M][K] * Bt[N][K]^T ----------------
#define BMt 128
#define BNt 128
#define BKt 64
__global__ __launch_bounds__(256) void gemm_bf16_bt(
    const unsigned short* __restrict__ A,   // [M][K] bf16 bits
    const unsigned short* __restrict__ Bt,  // [N][K] bf16 bits
    float* __restrict__ C,                  // [M][N] f32 (row stride = N)
    int M, int N, int K) {
  __shared__ unsigned short sA[BMt * BKt];
  __shared__ unsigned short sB[BNt * BKt];
  int tid = threadIdx.x;
  int lane = tid & 63;
  int wave = tid >> 6;
  int bm = blockIdx.x * BMt;
  int bn = blockIdx.y * BNt;
  int wr = (wave >> 1) * 64;
  int wc = (wave & 1) * 64;
  f32x4 acc[4][4];
  #pragma unroll
  for (int i = 0; i < 4; ++i)
    #pragma unroll
    for (int j = 0; j < 4; ++j) acc[i][j] = (f32x4){0.f, 0.f, 0.f, 0.f};
  int lr = lane & 15, lg = lane >> 4;
  for (int k0 = 0; k0 < K; k0 += BKt) {
    __syncthreads();
    #pragma unroll
    for (int q = 0; q < 4; ++q) {
      int c = tid + 256 * q;           // 0..1023: 128 rows x 8 chunks of 8 bf16
      int r = c >> 3, ch = c & 7;
      int sw = ch ^ (r & 7);           // XOR swizzle kills stride-128B bank conflict
      u32x4 va = *(const u32x4*)(A + (size_t)(bm + r) * K + k0 + ch * 8);
      *(u32x4*)(sA + r * BKt + sw * 8) = va;
      u32x4 vb = (u32x4){0u, 0u, 0u, 0u};
      if (bn + r < N) vb = *(const u32x4*)(Bt + (size_t)(bn + r) * K + k0 + ch * 8);
      *(u32x4*)(sB + r * BKt + sw * 8) = vb;
    }
    __syncthreads();
    #pragma unroll
    for (int kk = 0; kk < BKt; kk += 32) {
      s16x8 af[4], bfr[4];
      int ch = (kk >> 3) + lg;
      #pragma unroll
      for (int i = 0; i < 4; ++i) {
        int row = wr + i * 16 + lr;
        af[i] = *(const s16x8*)(sA + row * BKt + (ch ^ (row & 7)) * 8);
        int col = wc + i * 16 + lr;
        bfr[i] = *(const s16x8*)(sB + col * BKt + (ch ^ (col & 7)) * 8);
      }
      #pragma unroll
      for (int i = 0; i < 4; ++i)
        #pragma unroll
        for (int j = 0; j < 4; ++j)
          acc[i][j] = __builtin_amdgcn_mfma_f32_16x16x32_bf16(af[i], bfr[j], acc[i][j], 0, 0, 0);
    }
  }
  // C/D layout (HW-verified): col = lane&15, row = (lane>>4)*4 + reg
  #pragma unroll
  for (int i = 0; i < 4; ++i) {
    #pragma unroll
    for (int j = 0; j < 4; ++j) {
      int col = bn + wc + j * 16 + lr;
      if (col < N) {
        #pragma unroll
        for (int r = 0; r < 4; ++r) {
          int row = bm + wr + i * 16 + lg * 4 + r;
          C[(size_t)row * N + col] = acc[i][j][r];
        }
      }
    }
  }
}

// ---------------- split-bf16 MFMA GEMM for B/C/dt columns ----------------
// zx[r][4096+j] = x[r][:] . wbcdt[:][j], j<160, with fp32-grade accuracy:
// x = Ah+Al (bf16 hi/lo), w = Bh+Bl; product = Ah*Bh + Ah*Bl + Al*Bh
// (missing Al*Bl term is ~2^-18 relative). Replaces the f32 kernel whose
// 4KB-lane-stride wt loads hit 32 cache lines per instruction (r10: 360us).
__global__ __launch_bounds__(256) void gemm_bcdt_split3(
    const unsigned short* __restrict__ Ah, const unsigned short* __restrict__ Al,
    const unsigned short* __restrict__ Bh, const unsigned short* __restrict__ Bl,
    float* __restrict__ zx) {
  __shared__ unsigned short sAh[BMt * BKt], sAl[BMt * BKt];
  __shared__ unsigned short sBh[BMt * BKt], sBl[BMt * BKt];
  int tid = threadIdx.x;
  int lane = tid & 63;
  int wave = tid >> 6;
  int bm = blockIdx.x * BMt;
  int bn = blockIdx.y * BNt;
  int wr = (wave >> 1) * 64;
  int wc = (wave & 1) * 64;
  f32x4 acc[4][4];
  #pragma unroll
  for (int i = 0; i < 4; ++i)
    #pragma unroll
    for (int j = 0; j < 4; ++j) acc[i][j] = (f32x4){0.f, 0.f, 0.f, 0.f};
  int lr = lane & 15, lg = lane >> 4;
  for (int k0 = 0; k0 < D_MODELc; k0 += BKt) {
    __syncthreads();
    #pragma unroll
    for (int q = 0; q < 4; ++q) {
      int c = tid + 256 * q;
      int r = c >> 3, ch = c & 7;
      int sw = ch ^ (r & 7);
      size_t ga = (size_t)(bm + r) * D_MODELc + k0 + ch * 8;
      *(u32x4*)(sAh + r * BKt + sw * 8) = *(const u32x4*)(Ah + ga);
      *(u32x4*)(sAl + r * BKt + sw * 8) = *(const u32x4*)(Al + ga);
      u32x4 vh = (u32x4){0u, 0u, 0u, 0u}, vl = vh;
      if (bn + r < BCDTc) {
        size_t gb = (size_t)(bn + r) * D_MODELc + k0 + ch * 8;
        vh = *(const u32x4*)(Bh + gb);
        vl = *(const u32x4*)(Bl + gb);
      }
      *(u32x4*)(sBh + r * BKt + sw * 8) = vh;
      *(u32x4*)(sBl + r * BKt + sw * 8) = vl;
    }
    __syncthreads();
    #pragma unroll
    for (int kk = 0; kk < BKt; kk += 32) {
      s16x8 afh[4], afl[4], bfh[4], bfl[4];
      int ch = (kk >> 3) + lg;
      #pragma unroll
      for (int i = 0; i < 4; ++i) {
        int row = wr + i * 16 + lr;
        int ro = row * BKt + ((ch ^ (row & 7)) * 8);
        afh[i] = *(const s16x8*)(sAh + ro);
        afl[i] = *(const s16x8*)(sAl + ro);
        int col = wc + i * 16 + lr;
        int co = col * BKt + ((ch ^ (col & 7)) * 8);
        bfh[i] = *(const s16x8*)(sBh + co);
        bfl[i] = *(const s16x8*)(sBl + co);
      }
      #pragma unroll
      for (int i = 0; i < 4; ++i)
        #pragma unroll
        for (int j = 0; j < 4; ++j) {
          acc[i][j] = __builtin_amdgcn_mfma_f32_16x16x32_bf16(afh[i], bfh[j], acc[i][j], 0, 0, 0);
          acc[i][j] = __builtin_amdgcn_mfma_f32_16x16x32_bf16(afh[i], bfl[j], acc[i][j], 0, 0, 0);
          acc[i][j] = __builtin_amdgcn_mfma_f32_16x16x32_bf16(afl[i], bfh[j], acc[i][j], 0, 0, 0);
        }
    }
  }
  #pragma unroll
  for (int i = 0; i < 4; ++i) {
    #pragma unroll
    for (int j = 0; j < 4; ++j) {
      int col = bn + wc + j * 16 + lr;
      if (col < BCDTc) {
        #pragma unroll
        for (int r = 0; r < 4; ++r) {
          int row = bm + wr + i * 16 + lg * 4 + r;
          zx[(size_t)row * NPROJc + 2 * D_INNERc + col] = acc[i][j][r];
        }
      }
    }
  }
}

// ---------------- prep: softplus/decay + rope cos/sin tables ----------------
__global__ void prep_kernel(const float* __restrict__ zx, const float* __restrict__ dt_bias,
                            const float* __restrict__ A_log, float* __restrict__ dtdec,
                            float* __restrict__ cstab) {
  int idx = blockIdx.x * 256 + threadIdx.x;   // (b*L + l)*32 + h, 131072 total
  int h = idx & 31;
  int bl = idx >> 5;
  float raw = zx[(size_t)bl * NPROJc + (2 * D_INNERc + 128) + h] + dt_bias[h];
  float dt = fmaxf(raw, 0.f) + log1pf(expf(-fabsf(raw)));
  float dec = expf(-expf(A_log[h]) * dt);
  dtdec[(size_t)idx * 2] = dt;
  dtdec[(size_t)idx * 2 + 1] = dec;
  #pragma unroll
  for (int k = 0; k < PAIRSc; ++k) {
    float invf = expf(-(float)k * 0.575646273248511f); // ln(10000)/16
    float ang = dt * invf;
    float sv, cv;
    sincosf(ang, &sv, &cv);
    cstab[((size_t)idx * PAIRSc + k) * 2] = cv;
    cstab[((size_t)idx * PAIRSc + k) * 2 + 1] = sv;
  }
}

// ================= chunk-parallel scan (r10-proven) =================
__global__ __launch_bounds__(256) void scan_local(
    const float* __restrict__ zx, const float* __restrict__ dtdec,
    const float* __restrict__ cstab, float* __restrict__ fbuf,
    float* __restrict__ agg) {
  int bid = blockIdx.x;
  int bh = bid >> 5, c = bid & 31;
  int b = bh >> 5, h = bh & 31;
  int tid = threadIdx.x;
  int w = tid >> 6;
  int p = tid & 63;
  float hr[16];
  #pragma unroll
  for (int i = 0; i < 16; ++i) hr[i] = 0.f;
  float sdt = 0.f, pdec = 1.f;
  const float* zrow = zx + (size_t)b * LSEQc * NPROJc;
  const float* ddp = dtdec + ((size_t)b * LSEQc * NHEADSc + h) * 2;
  const float* csp = cstab + (((size_t)b * LSEQc * NHEADSc + h) * PAIRSc + 4 * w) * 2;
  int xoff   = D_INNERc + h * 64 + p;
  int brope  = 2 * D_INNERc + 8 * w;
  int bplain = 2 * D_INNERc + 32 + 8 * w;
  int t0 = c * CLc;
  for (int s = 0; s < CLc; ++s) {
    int t = t0 + s;
    const float* zr = zrow + (size_t)t * NPROJc;
    f4 bra = *(const f4*)(zr + brope),  brb = *(const f4*)(zr + brope + 4);
    f4 bpa = *(const f4*)(zr + bplain), bpb = *(const f4*)(zr + bplain + 4);
    f4 cva = *(const f4*)(csp + (size_t)t * (NHEADSc * PAIRSc * 2));
    f4 cvb = *(const f4*)(csp + (size_t)t * (NHEADSc * PAIRSc * 2) + 4);
    f2 dd = *(const f2*)(ddp + (size_t)t * (NHEADSc * 2));
    float dt = dd.x, dec = dd.y;
    float xv = zr[xoff];
    float dxp = dt * xv;
    #pragma unroll
    for (int k = 0; k < 4; ++k) {
      f4 cvv = (k < 2) ? cva : cvb;
      float cc = cvv[(k & 1) * 2], ss = cvv[(k & 1) * 2 + 1];
      float cd = dec * cc, sd = dec * ss;
      f4 bv = (k < 2) ? bra : brb;
      float b1 = bv[(2 * k) & 3], b2 = bv[(2 * k + 1) & 3];
      float h1 = hr[2 * k], h2 = hr[2 * k + 1];
      hr[2 * k]     = fmaf(cd, h1, fmaf(-sd, h2, b1 * dxp));
      hr[2 * k + 1] = fmaf(sd, h1, fmaf(cd, h2, b2 * dxp));
    }
    #pragma unroll
    for (int i = 0; i < 8; ++i) {
      f4 bv = (i < 4) ? bpa : bpb;
      hr[8 + i] = fmaf(dec, hr[8 + i], bv[i & 3] * dxp);
    }
    sdt += dt;
    pdec *= dec;
  }
  float* fslot = fbuf + (size_t)(bh * NCHc + c) * (64 * 64);
  #pragma unroll
  for (int i = 0; i < 8; ++i) {
    fslot[(8 * w + i) * 64 + p]      = hr[i];
    fslot[(32 + 8 * w + i) * 64 + p] = hr[8 + i];
  }
  if (tid == 0) {
    agg[(bh * NCHc + c) * 2]     = sdt;
    agg[(bh * NCHc + c) * 2 + 1] = pdec;
  }
}

__global__ __launch_bounds__(256) void scan_phase2(
    float* __restrict__ fbuf, const float* __restrict__ agg) {
  int bh = blockIdx.x;
  int tid = threadIdx.x;
  int w = tid >> 6;
  int p = tid & 63;
  float hr[16];
  #pragma unroll
  for (int i = 0; i < 16; ++i) hr[i] = 0.f;
  float invfk[4];
  #pragma unroll
  for (int kk = 0; kk < 4; ++kk)
    invfk[kk] = expf(-(float)(4 * w + kk) * 0.575646273248511f);
  for (int c = 1; c < NCHc; ++c) {
    f2 ag = *(const f2*)(agg + (size_t)(bh * NCHc + c - 1) * 2);
    float sdt = ag.x, pd = ag.y;
    float* fslot = fbuf + (size_t)(bh * NCHc + c - 1) * (64 * 64);
    #pragma unroll
    for (int kk = 0; kk < 4; ++kk) {
      float th = sdt * invfk[kk];
      float sn, cs_;
      __sincosf(th, &sn, &cs_);
      float cdp = pd * cs_, sdp = pd * sn;
      int n1 = 8 * w + 2 * kk;
      float f1 = fslot[n1 * 64 + p], f2v = fslot[(n1 + 1) * 64 + p];
      float h1 = hr[2 * kk], h2 = hr[2 * kk + 1];
      hr[2 * kk]     = fmaf(cdp, h1, fmaf(-sdp, h2, f1));
      hr[2 * kk + 1] = fmaf(sdp, h1, fmaf(cdp, h2, f2v));
    }
    #pragma unroll
    for (int i = 0; i < 8; ++i) {
      int n = 32 + 8 * w + i;
      hr[8 + i] = fmaf(pd, hr[8 + i], fslot[n * 64 + p]);
    }
    #pragma unroll
    for (int i = 0; i < 8; ++i) {
      fslot[(8 * w + i) * 64 + p]      = hr[i];
      fslot[(32 + 8 * w + i) * 64 + p] = hr[8 + i];
    }
  }
}

__global__ __launch_bounds__(256) void scan_fix(
    const float* __restrict__ zx, const float* __restrict__ dtdec,
    const float* __restrict__ cstab, const float* __restrict__ Dskip,
    const float* __restrict__ fbuf, float* __restrict__ yout) {
  int bid = blockIdx.x;
  int bh = bid >> 5, c = bid & 31;
  int b = bh >> 5, h = bh & 31;
  int tid = threadIdx.x;
  int w = tid >> 6;
  int p = tid & 63;
  __shared__ float ylds[4][32][64];   // 32 KiB
  float hr[16];
  if (c == 0) {
    #pragma unroll
    for (int i = 0; i < 16; ++i) hr[i] = 0.f;
  } else {
    const float* fslot = fbuf + (size_t)(bh * NCHc + c - 1) * (64 * 64);
    #pragma unroll
    for (int i = 0; i < 8; ++i) {
      hr[i]     = fslot[(8 * w + i) * 64 + p];
      hr[8 + i] = fslot[(32 + 8 * w + i) * 64 + p];
    }
  }
  float dsk = Dskip[h];
  const float* zrow = zx + (size_t)b * LSEQc * NPROJc;
  const float* ddp = dtdec + ((size_t)b * LSEQc * NHEADSc + h) * 2;
  const float* csp = cstab + (((size_t)b * LSEQc * NHEADSc + h) * PAIRSc + 4 * w) * 2;
  int xoff   = D_INNERc + h * 64 + p;
  int brope  = 2 * D_INNERc + 8 * w;
  int bplain = 2 * D_INNERc + 32 + 8 * w;
  int crope  = 2 * D_INNERc + 64 + 8 * w;
  int cplain = 2 * D_INNERc + 64 + 32 + 8 * w;
  float* ybase = yout + (size_t)b * LSEQc * D_INNERc + h * 64 + p;
  int t0c = c * CLc;
  #pragma unroll 1
  for (int half = 0; half < 2; ++half) {
    int tb = t0c + half * 32;
    #pragma unroll 1
    for (int s = 0; s < 32; ++s) {
      int t = tb + s;
      const float* zr = zrow + (size_t)t * NPROJc;
      f4 bra = *(const f4*)(zr + brope),  brb = *(const f4*)(zr + brope + 4);
      f4 bpa = *(const f4*)(zr + bplain), bpb = *(const f4*)(zr + bplain + 4);
      f4 cra = *(const f4*)(zr + crope),  crb = *(const f4*)(zr + crope + 4);
      f4 cqa = *(const f4*)(zr + cplain), cqb = *(const f4*)(zr + cplain + 4);
      f4 cva = *(const f4*)(csp + (size_t)t * (NHEADSc * PAIRSc * 2));
      f4 cvb = *(const f4*)(csp + (size_t)t * (NHEADSc * PAIRSc * 2) + 4);
      f2 dd = *(const f2*)(ddp + (size_t)t * (NHEADSc * 2));
      float dt = dd.x, dec = dd.y;
      float xv = zr[xoff];
      float dxp = dt * xv;
      float yp = 0.f;
      #pragma unroll
      for (int k = 0; k < 4; ++k) {
        f4 cvv = (k < 2) ? cva : cvb;
        float cc = cvv[(k & 1) * 2], ss = cvv[(k & 1) * 2 + 1];
        float cd = dec * cc, sd = dec * ss;
        f4 bv = (k < 2) ? bra : brb;
        float b1 = bv[(2 * k) & 3], b2 = bv[(2 * k + 1) & 3];
        f4 cvC = (k < 2) ? cra : crb;
        float c1 = cvC[(2 * k) & 3], c2 = cvC[(2 * k + 1) & 3];
        float h1 = hr[2 * k], h2 = hr[2 * k + 1];
        float n1 = fmaf(cd, h1, fmaf(-sd, h2, b1 * dxp));
        float n2 = fmaf(sd, h1, fmaf(cd, h2, b2 * dxp));
        hr[2 * k] = n1; hr[2 * k + 1] = n2;
        yp = fmaf(c1, n1, yp);
        yp = fmaf(c2, n2, yp);
      }
      #pragma unroll
      for (int i = 0; i < 8; ++i) {
        f4 bv = (i < 4) ? bpa : bpb;
        f4 cv = (i < 4) ? cqa : cqb;
        float hn = fmaf(dec, hr[8 + i], bv[i & 3] * dxp);
        hr[8 + i] = hn;
        yp = fmaf(cv[i & 3], hn, yp);
      }
      if (w == 0) yp = fmaf(dsk, xv, yp);
      ylds[w][s][p] = yp;
    }
    __syncthreads();
    int sq = tid >> 6;
    #pragma unroll
    for (int i = 0; i < 8; ++i) {
      int s = sq * 8 + i;
      float sum = ylds[0][s][p] + ylds[1][s][p] + ylds[2][s][p] + ylds[3][s][p];
      ybase[(size_t)(tb + s) * D_INNERc] = sum;
    }
    __syncthreads();
  }
}

// ---------------- fused silu-gate + RMSNorm -> bf16 ----------------
__global__ __launch_bounds__(256) void epilogue_kernel(
    const float* __restrict__ yout, const float* __restrict__ zx,
    const float* __restrict__ nw, unsigned short* __restrict__ gn) {
  int r = blockIdx.x;
  int tid = threadIdx.x;
  const float* yr = yout + (size_t)r * D_INNERc;
  const float* zr = zx + (size_t)r * NPROJc;   // z = first 2048 cols
  float g[8];
  float ss = 0.f;
  #pragma unroll
  for (int q = 0; q < 2; ++q) {
    int j = tid * 4 + q * 1024;
    f4 y = *(const f4*)(yr + j);
    f4 z = *(const f4*)(zr + j);
    #pragma unroll
    for (int e = 0; e < 4; ++e) {
      float zz = z[e];
      float sig = 1.f / (1.f + expf(-zz));
      float gg = y[e] * zz * sig;
      g[q * 4 + e] = gg;
      ss = fmaf(gg, gg, ss);
    }
  }
  #pragma unroll
  for (int o = 1; o < 64; o <<= 1) ss += __shfl_xor(ss, o);
  __shared__ float red[4];
  int wv = tid >> 6, lane = tid & 63;
  if (lane == 0) red[wv] = ss;
  __syncthreads();
  float tot = red[0] + red[1] + red[2] + red[3];
  float scale = rsqrtf(tot * (1.f / 2048.f) + 1e-5f);
  #pragma unroll
  for (int q = 0; q < 2; ++q) {
    int j = tid * 4 + q * 1024;
    f4 wn = *(const f4*)(nw + j);
    u16x4 o = { f2bf(g[q * 4 + 0] * scale * wn[0]),
                f2bf(g[q * 4 + 1] * scale * wn[1]),
                f2bf(g[q * 4 + 2] * scale * wn[2]),
                f2bf(g[q * 4 + 3] * scale * wn[3]) };
    *(u16x4*)(gn + (size_t)r * D_INNERc + j) = o;
  }
}

// ---------------- workspace layout (bytes) ----------------
#define Z_OFF      0ull                     // zxbcdt f32 [4096][4256]  = 69,730,304
#define XB_OFF     69730304ull              // x bf16 hi [4096][1024]   =  8,388,608
#define WTIN_OFF   78118912ull              // W_in^T bf16 [4256][1024] =  8,716,288
#define WTOUT_OFF  86835200ull              // W_out^T bf16 [1024][2048]=  4,194,304
#define DTDEC_OFF  91029504ull              // f32 [131072][2]          =  1,048,576
#define CS_OFF     92078080ull              // f32 [131072][16][2]      = 16,777,216
#define YOUT_OFF   108855296ull             // f32 [4096][2048]         = 33,554,432
#define GN_OFF     142409728ull             // bf16 [4096][2048]        = 16,777,216
// scratch region (temporally disjoint uses):
//   pre-scan:  xlo / wbh / wbl (bcdt split operands)
//   scan:      fbuf (chunk states)  -- aliases the above, all dead by then
#define XLO_OFF    159186944ull             // bf16 lo [4096][1024]     =  8,388,608
#define WBH_OFF    167575552ull             // bf16 hi [160][1024]      =    327,680
#define WBL_OFF    167903232ull             // bf16 lo [160][1024]      =    327,680
#define FB_OFF     159186944ull             // f32 [64][32][64][64]     = 33,554,432 (alias)
#define AGG_OFF    192741376ull             // f32 [64][32][2]          =     16,384
// total 192,757,760 bytes

extern "C" void kernel_launch(void* const* d_in, const int* in_sizes, int n_in,
                              void* d_out, int out_size, void* d_ws, size_t ws_size,
                              hipStream_t stream) {
  (void)in_sizes; (void)n_in; (void)out_size; (void)ws_size;
  const float* x        = (const float*)d_in[0];
  const float* W_in     = (const float*)d_in[1];
  const float* W_out    = (const float*)d_in[2];
  const float* dt_bias  = (const float*)d_in[3];
  const float* A_log    = (const float*)d_in[4];
  const float* D_skip   = (const float*)d_in[5];
  const float* norm_w   = (const float*)d_in[6];

  char* ws = (char*)d_ws;
  float* zx              = (float*)(ws + Z_OFF);
  unsigned short* xb     = (unsigned short*)(ws + XB_OFF);
  unsigned short* wtin   = (unsigned short*)(ws + WTIN_OFF);
  unsigned short* wtout  = (unsigned short*)(ws + WTOUT_OFF);
  float* dtdec           = (float*)(ws + DTDEC_OFF);
  float* cstab           = (float*)(ws + CS_OFF);
  float* yout            = (float*)(ws + YOUT_OFF);
  unsigned short* gn     = (unsigned short*)(ws + GN_OFF);
  unsigned short* xlo    = (unsigned short*)(ws + XLO_OFF);
  unsigned short* wbh    = (unsigned short*)(ws + WBH_OFF);
  unsigned short* wbl    = (unsigned short*)(ws + WBL_OFF);
  float* fbuf            = (float*)(ws + FB_OFF);
  float* agg             = (float*)(ws + AGG_OFF);
  float* out             = (float*)d_out;

  // convert x -> bf16 hi + lo
  cvt_bf16_split<<<4096, 256, 0, stream>>>(x, xb, xlo, (ROWSc * D_MODELc) / 4);
  // W_in [1024][4256] -> [4256][1024] bf16 (z/x rows used by gemm1)
  transpose_to_bf16<<<dim3(133, 32), dim3(32, 8), 0, stream>>>(W_in, wtin, 1024, 4256);
  // W_out [2048][1024] -> [1024][2048] bf16
  transpose_to_bf16<<<dim3(32, 64), dim3(32, 8), 0, stream>>>(W_out, wtout, 2048, 1024);
  // BCdt weight block -> bf16 hi/lo [160][1024]
  transpose_wb_bf16<<<dim3(5, 32), dim3(32, 8), 0, stream>>>(W_in, wbh, wbl);

  // zxbcdt z/x columns (0..4095) via bf16 MFMA GEMM
  gemm_bf16_bt<<<dim3(ROWSc / BMt, 32), 256, 0, stream>>>(
      xb, wtin, zx, ROWSc, NPROJc, D_MODELc);

  // B/C/dt columns (4096..4255) via split-bf16 3-product MFMA (fp32-grade)
  gemm_bcdt_split3<<<dim3(ROWSc / BMt, 2), 256, 0, stream>>>(xb, xlo, wbh, wbl, zx);

  // dt/decay/cos/sin tables
  prep_kernel<<<(BSZc * LSEQc * NHEADSc) / 256, 256, 0, stream>>>(zx, dt_bias, A_log, dtdec, cstab);

  // chunk-parallel scan: local scans -> sequential composition -> fix-up
  scan_local<<<BSZc * NHEADSc * NCHc, 256, 0, stream>>>(zx, dtdec, cstab, fbuf, agg);
  scan_phase2<<<BSZc * NHEADSc, 256, 0, stream>>>(fbuf, agg);
  scan_fix<<<BSZc * NHEADSc * NCHc, 256, 0, stream>>>(zx, dtdec, cstab, D_skip, fbuf, yout);

  // silu gate + RMSNorm -> bf16
  epilogue_kernel<<<ROWSc, 256, 0, stream>>>(yout, zx, norm_w, gn);

  // out = gn @ W_out
  gemm_bf16_bt<<<dim3(ROWSc / BMt, D_MODELc / BNt), 256, 0, stream>>>(
      gn, wtout, out, ROWSc, D_MODELc, D_INNERc);
}